// Round 4
// baseline (327.731 us; speedup 1.0000x reference)
//
#include <hip/hip_runtime.h>
#include <cmath>

#define HH 1024
#define WW 1024
#define KS 51
#define RAD 25
#define PLANE (HH * WW)
#define TROWS 128
#define LROWS (TROWS + KS - 1)   // 178

struct GaussW { float w[KS]; };

// ---------------------------------------------------------------------------
// Horizontal 51-tap blur, FULLY COALESCED (R1-R3 plateaued at ~1.4 TB/s
// effective BW: 64B lane stride w/ 16B accesses = 4x line-request
// amplification). Thread = 4 consecutive outputs (c = seg*256 + lane*4) so
// every float4 load/store instruction is lane-contiguous. 15 guarded float4
// loads, consume-immediately FMA (low VGPR). Weights -> SGPRs via kernarg.
// Block = 1 row x 4 segments (4 waves).
// ---------------------------------------------------------------------------
__global__ __launch_bounds__(256) void hblur_kernel(const float* __restrict__ x,
                                                    float* __restrict__ tmp,
                                                    GaussW gw)
{
    const int t    = threadIdx.x;
    const int lane = t & 63;
    const int seg  = t >> 6;                    // wave-uniform
    const long long row = blockIdx.x;
    const float* src = x + row * WW;
    const int c = seg * 256 + lane * 4;         // outputs c..c+3

    float acc[4] = {0.f, 0.f, 0.f, 0.f};

    #pragma unroll
    for (int q = 0; q < 15; q++) {
        const int b = c - 28 + q * 4;           // 16B-aligned, lane-contiguous
        float4 v;
        if (b >= 0 && b <= WW - 4) {
            v = *(const float4*)(src + b);
        } else {                                 // few edge lanes only
            float tv[4];
            #pragma unroll
            for (int e = 0; e < 4; e++) {
                const int cc = b + e;
                tv[e] = (cc >= 0 && cc < WW) ? src[cc] : 0.f;
            }
            v = make_float4(tv[0], tv[1], tv[2], tv[3]);
        }
        const float ve[4] = {v.x, v.y, v.z, v.w};
        #pragma unroll
        for (int e = 0; e < 4; e++) {
            #pragma unroll
            for (int d = 0; d < 4; d++) {
                const int k = q * 4 + e - 3 - d;    // compile-time tap index
                if (k >= 0 && k < KS)
                    acc[d] = fmaf(gw.w[k], ve[e], acc[d]);
            }
        }
    }

    *(float4*)(tmp + row * WW + c) = make_float4(acc[0], acc[1], acc[2], acc[3]);
}

// ---------------------------------------------------------------------------
// Vertical 51-tap blur + screen blend + clamp, LDS-tiled.
// Block stages a 64-col x 178-row tmp tile into LDS (45.5 KB, all loads
// lane-contiguous, each element fetched ONCE -> halo amp 1.39x), then each
// thread computes 1 col x 32 rows (2 passes of 16 accs) reading LDS
// column-wise: per tap, 64 lanes read 64 consecutive floats = 2 lanes/bank
// (free). x/out accesses lane-contiguous 256B/instr.
// ---------------------------------------------------------------------------
__global__ __launch_bounds__(256) void vblend_kernel(const float* __restrict__ tmp,
                                                     const float* __restrict__ x,
                                                     float* __restrict__ out,
                                                     GaussW gw,
                                                     const float* __restrict__ amountp)
{
    __shared__ float ht[LROWS * 64];
    const int t      = threadIdx.x;
    const int bid    = blockIdx.x;
    const int plane  = bid >> 7;            // 128 tiles per plane
    const int rem    = bid & 127;
    const int tile_x = rem >> 3;            // 16 col-strips of 64
    const int tile_y = rem & 7;             // inner -> vertical halo L2 reuse
    const int c0     = tile_x * 64;
    const int r0     = tile_y * TROWS;
    const float* tp  = tmp + (size_t)plane * PLANE;

    // cooperative staging: 178 rows x 16 float4-cols = 2848 float4 tasks
    #pragma unroll
    for (int i = 0; i < 12; i++) {
        const int idx = i * 256 + t;
        if (idx < LROWS * 16) {
            const int lr = idx >> 4;
            const int cf = idx & 15;
            const int gr = r0 - RAD + lr;
            float4 v = make_float4(0.f, 0.f, 0.f, 0.f);
            if (gr >= 0 && gr < HH)
                v = *(const float4*)(tp + (size_t)gr * WW + c0 + cf * 4);
            *(float4*)(&ht[lr * 64 + cf * 4]) = v;
        }
    }
    __syncthreads();

    const float p = amountp[0];
    const float s = 1.2f * (0.4f / (1.f + expf(-p)));   // 1.2 * amount

    const int col = t & 63;
    const int rg  = t >> 6;                 // 4 row-groups x 32 rows
    const float* xp = x   + (size_t)plane * PLANE + c0 + col;
    float*       op = out + (size_t)plane * PLANE + c0 + col;

    #pragma unroll
    for (int pass = 0; pass < 2; pass++) {
        const int lr0 = rg * 32 + pass * 16;     // local output row base
        float acc[16];
        #pragma unroll
        for (int j = 0; j < 16; j++) acc[j] = 0.f;

        #pragma unroll
        for (int i = 0; i < 66; i++) {
            const float v = ht[(lr0 + i) * 64 + col];   // conflict-free
            #pragma unroll
            for (int j = 0; j < 16; j++) {
                const int k = i - j;                    // compile-time tap
                if (k >= 0 && k < KS)
                    acc[j] = fmaf(gw.w[k], v, acc[j]);
            }
        }

        #pragma unroll
        for (int j = 0; j < 16; j++) {
            const size_t off = (size_t)(r0 + lr0 + j) * WW;
            const float xv = xp[off];
            float res = 1.f - (1.f - xv) * (1.f - s * acc[j]);
            op[off] = fminf(fmaxf(res, 0.f), 1.f);
        }
    }
}

// ---------------------------------------------------------------------------
extern "C" void kernel_launch(void* const* d_in, const int* in_sizes, int n_in,
                              void* d_out, int out_size, void* d_ws, size_t ws_size,
                              hipStream_t stream)
{
    const float* x       = (const float*)d_in[0];
    const float* amountp = (const float*)d_in[1];
    float* out = (float*)d_out;
    float* tmp = (float*)d_ws;

    // Gaussian weights (sigma=15, size 51), normalized — identical every call.
    GaussW gw;
    {
        double e[KS], sum = 0.0;
        for (int i = 0; i < KS; i++) {
            const double d = (double)(i - RAD);
            e[i] = exp(-d * d / (2.0 * 15.0 * 15.0));
            sum += e[i];
        }
        for (int i = 0; i < KS; i++) gw.w[i] = (float)(e[i] / sum);
    }

    const int total_planes = in_sizes[0] / PLANE;      // 24
    const size_t plane_bytes = (size_t)PLANE * sizeof(float);
    int P = (int)(ws_size / plane_bytes);
    if (P < 1) P = 1;
    if (P > total_planes) P = total_planes;

    for (int p0 = 0; p0 < total_planes; p0 += P) {
        const int pc = (total_planes - p0 < P) ? (total_planes - p0) : P;
        hblur_kernel<<<pc * 1024, 256, 0, stream>>>(x + (size_t)p0 * PLANE, tmp, gw);
        vblend_kernel<<<pc * 128, 256, 0, stream>>>(tmp,
                                                    x + (size_t)p0 * PLANE,
                                                    out + (size_t)p0 * PLANE,
                                                    gw, amountp);
    }
}